// Round 7
// baseline (435.328 us; speedup 1.0000x reference)
//
#include <hip/hip_runtime.h>

// SelfAttentionBlock: x[8,2048,512]; Wq/Wk/Wv [512,512]; bq/bk/bv [512].
// out[8,2048,1024] = concat(x, causal_softmax(QK^T/sqrt(512)) @ V).
// v7: v5 attn interior (4 barriers/tile, wave-autonomous softmax) + split-K
// over 2 key-halves (512 blocks, heavy-first, 2 blocks/CU) + combine kernel.

#define DEV __device__ __forceinline__

typedef unsigned short u16;
typedef unsigned int u32;
typedef __attribute__((ext_vector_type(8))) short short8;   // 8 bf16 = 4 VGPRs
typedef __attribute__((ext_vector_type(4))) float float4v;  // MFMA C/D frag

DEV u16 f2bf(float f) {
    u32 u = __float_as_uint(f);
    return (u16)((u + 0x7FFFu + ((u >> 16) & 1u)) >> 16);
}
DEV float bf2f(u16 h) { return __uint_as_float(((u32)h) << 16); }

DEV float4v mfma16(short8 a, short8 b, float4v c) {
    return __builtin_amdgcn_mfma_f32_16x16x32_bf16(a, b, c, 0, 0, 0);
}

// async global->LDS, 16B per lane; LDS dest = wave-uniform base + lane*16
#define GLD16(gptr, lptr)                                                     \
    __builtin_amdgcn_global_load_lds(                                         \
        (const __attribute__((address_space(1))) void*)(gptr),                \
        (__attribute__((address_space(3))) void*)(lptr), 16, 0, 0)

// ---------------- Kernel 0: detect input dtype ------------------------------
__global__ void detect_k(const u32* __restrict__ xw, int* __restrict__ flag) {
    __shared__ int sh[256];
    int tid = threadIdx.x;
    u32 w = xw[tid * 64];
    int e = (w >> 7) & 0xFF;
    sh[tid] = (e >= 0x60 && e <= 0x90) ? 1 : 0;
    __syncthreads();
    for (int s = 128; s > 0; s >>= 1) {
        if (tid < s) sh[tid] += sh[tid + s];
        __syncthreads();
    }
    if (tid == 0) flag[0] = (sh[0] > 128) ? 1 : 0;   // 1 = bf16
}

// ---------------- Kernel 1: canonicalize x -> xb; also write out[...,0:512] -
__global__ void convx_k(const void* __restrict__ x, const int* __restrict__ flag,
                        u16* __restrict__ xb, void* __restrict__ out) {
    int i0 = (blockIdx.x * 256 + threadIdx.x) * 8;
    int row = i0 >> 9, col = i0 & 511;
    if (flag[0]) {
        uint4 v = *(const uint4*)((const u16*)x + i0);
        *(uint4*)&xb[i0] = v;
        *(uint4*)((u16*)out + (size_t)row * 1024 + col) = v;
    } else {
        const float* xf = (const float*)x;
        float4 f0 = *(const float4*)(xf + i0);
        float4 f1 = *(const float4*)(xf + i0 + 4);
        union { u16 us[8]; uint4 v; } pk;
        pk.us[0] = f2bf(f0.x); pk.us[1] = f2bf(f0.y);
        pk.us[2] = f2bf(f0.z); pk.us[3] = f2bf(f0.w);
        pk.us[4] = f2bf(f1.x); pk.us[5] = f2bf(f1.y);
        pk.us[6] = f2bf(f1.z); pk.us[7] = f2bf(f1.w);
        *(uint4*)&xb[i0] = pk.v;
        float* o = (float*)out + (size_t)row * 1024 + col;
        *(float4*)o = f0; *(float4*)(o + 4) = f1;
    }
}

// ---------------- Kernel 2: transpose + canonicalize weights ----------------
__global__ void convw_k(const void* __restrict__ Wq, const void* __restrict__ Wk,
                        const void* __restrict__ Wv, const int* __restrict__ flag,
                        u16* __restrict__ Wt) {
    int z = blockIdx.y;
    const void* W = (z == 0) ? Wq : ((z == 1) ? Wk : Wv);
    int flat = blockIdx.x * 256 + threadIdx.x;   // = n*512 + k
    int n = flat >> 9, k = flat & 511;
    u16 v = flag[0] ? ((const u16*)W)[k * 512 + n]
                    : f2bf(((const float*)W)[k * 512 + n]);
    Wt[z * 262144 + flat] = v;
}

// ---------------- Kernel 3: canonicalize biases -----------------------------
__global__ void convb_k(const void* __restrict__ bq, const void* __restrict__ bk,
                        const void* __restrict__ bv, const int* __restrict__ flag,
                        u16* __restrict__ bb) {
    int i = blockIdx.x * 256 + threadIdx.x;      // 0..1535
    int z = i >> 9, n = i & 511;
    const void* s = (z == 0) ? bq : ((z == 1) ? bk : bv);
    bb[i] = flag[0] ? ((const u16*)s)[n] : f2bf(((const float*)s)[n]);
}

// ---------------- Kernel 4: QKV projection GEMM -----------------------------
__global__ __launch_bounds__(256) void proj_k(
        const u16* __restrict__ x, const u16* __restrict__ Wt,
        const u16* __restrict__ bb,
        u16* __restrict__ Qo, u16* __restrict__ Ko, u16* __restrict__ Vt_out) {
    int z = blockIdx.z;
    const u16* Wz = Wt + z * 262144;                       // Wz[n][k]
    const u16* bias = bb + z * 512;
    int mBase = blockIdx.x * 128;
    int nBase = blockIdx.y * 128;

    __shared__ __attribute__((aligned(16))) u16 Xs[128 * 32];
    __shared__ __attribute__((aligned(16))) u16 Ws[128 * 32];

    int tid = threadIdx.x;
    int w = tid >> 6, lane = tid & 63, quad = lane >> 4, l16 = lane & 15;
    int wr = (w >> 1) * 64, wc = (w & 1) * 64;

    float4v acc[4][4] = {};

    for (int k0 = 0; k0 < 512; k0 += 32) {
        #pragma unroll
        for (int gg = 0; gg < 2; gg++) {                   // 1KB granules
            int g = w * 2 + gg;
            int row = g * 16 + (lane >> 2);
            int col8 = lane & 3;
            GLD16(&x [(size_t)(mBase + row) * 512 + k0 + col8 * 8], &Xs[g * 512]);
            GLD16(&Wz[(size_t)(nBase + row) * 512 + k0 + col8 * 8], &Ws[g * 512]);
        }
        __syncthreads();

        short8 a[4], b[4];
        #pragma unroll
        for (int mt = 0; mt < 4; mt++)
            a[mt] = *(const short8*)&Xs[(wr + mt * 16 + l16) * 32 + quad * 8];
        #pragma unroll
        for (int nt = 0; nt < 4; nt++)
            b[nt] = *(const short8*)&Ws[(wc + nt * 16 + l16) * 32 + quad * 8];
        #pragma unroll
        for (int mt = 0; mt < 4; mt++)
            #pragma unroll
            for (int nt = 0; nt < 4; nt++)
                acc[mt][nt] = mfma16(a[mt], b[nt], acc[mt][nt]);
        __syncthreads();
    }

    #pragma unroll
    for (int nt = 0; nt < 4; nt++) {
        int n = nBase + wc + nt * 16 + l16;
        float bval = bf2f(bias[n]);
        #pragma unroll
        for (int mt = 0; mt < 4; mt++) {
            int m0 = mBase + wr + mt * 16 + quad * 4;
            float4v v = acc[mt][nt];
            if (z == 2) {
                int bbi = m0 >> 11, tt = m0 & 2047;        // Vt[b][d=n][t]
                u16 t0 = f2bf(v[0] + bval), t1 = f2bf(v[1] + bval);
                u16 t2 = f2bf(v[2] + bval), t3 = f2bf(v[3] + bval);
                uint2 pk = make_uint2((u32)t0 | ((u32)t1 << 16), (u32)t2 | ((u32)t3 << 16));
                *(uint2*)&Vt_out[((size_t)bbi * 512 + n) * 2048 + tt] = pk;
            } else {
                u16* dst = (z == 0) ? Qo : Ko;
                #pragma unroll
                for (int r = 0; r < 4; r++)
                    dst[(size_t)(m0 + r) * 512 + n] = f2bf(v[r] + bval);
            }
        }
    }
}

// ---------------- Kernel 5: flash attention v7 ------------------------------
// v5 interior. dosplit=1: 512 blocks = (qt desc)*16 + h*8 + b, key-half h,
// unnormalized bf16 O + (m,l) partials. dosplit=0: 256 blocks, direct write.

#define LOADK(dst, kB, half)                                                  \
    { _Pragma("unroll")                                                       \
      for (int j = 0; j < 8; j++) {                                           \
        int row2 = 2 * (j * 4 + w);                                           \
        int row = row2 + (lane >> 5);                                         \
        int col8 = lane & 31;                                                 \
        GLD16(&Kb[(size_t)((kB) + row) * 512 + (half) * 256 +                 \
                  ((col8 ^ (row & 7)) << 3)], &dst[row2 * 256]);              \
      } }

#define LOADV(dst, kB, half)                                                  \
    { _Pragma("unroll")                                                       \
      for (int j = 0; j < 8; j++) {                                           \
        int blk8 = 8 * (j * 4 + w);                                           \
        int dl = blk8 + (lane >> 3);                                          \
        int col8 = lane & 7;                                                  \
        GLD16(&Vb[(size_t)((half) * 256 + dl) * 2048 + (kB) +                 \
                  ((col8 ^ (dl & 7)) << 3)], &dst[blk8 * 64]);                \
      } }

#define SSTEP(buf, h)                                                         \
    { _Pragma("unroll")                                                       \
      for (int kk = 0; kk < 8; kk++) {                                        \
        _Pragma("unroll")                                                     \
        for (int nt = 0; nt < 4; nt++) {                                      \
          short8 bf = *(const short8*)&buf[(nt * 16 + l16) * 256 +            \
                                           (((kk * 4 + quad) ^ sw) << 3)];    \
          accS[nt] = mfma16(qf[(h) * 8 + kk], bf, accS[nt]);                  \
        } } }

#define PVSTEP(buf, accO)                                                     \
    { _Pragma("unroll")                                                       \
      for (int kk = 0; kk < 2; kk++) {                                        \
        _Pragma("unroll")                                                     \
        for (int dt = 0; dt < 4; dt++) {                                      \
          int rowv = w * 64 + dt * 16 + l16;                                  \
          short8 bf = *(const short8*)&buf[rowv * 64 +                        \
                                           (((kk * 4 + quad) ^ sw) << 3)];    \
          _Pragma("unroll")                                                   \
          for (int mt = 0; mt < 4; mt++)                                      \
            accO[dt][mt] = mfma16(pf[mt][kk], bf, accO[dt][mt]);              \
        } } }

__global__ __launch_bounds__(256, 2) void attn_k(
        const u16* __restrict__ Q, const u16* __restrict__ K,
        const u16* __restrict__ Vt, const int* __restrict__ flag,
        void* __restrict__ out, u16* __restrict__ Opart,
        float2* __restrict__ ml, int dosplit) {
    int blk = blockIdx.x;
    int b, qt, h, kt0, kt1;
    if (dosplit) {
        qt = 31 - (blk >> 4);
        h  = (blk >> 3) & 1;
        b  = blk & 7;
        int n = qt + 1, mid = n >> 1;
        kt0 = h ? mid : 0;
        kt1 = h ? n : mid;
    } else {
        qt = 31 - (blk >> 3);
        h  = 0;
        b  = blk & 7;
        kt0 = 0; kt1 = qt + 1;
    }
    int q0 = qt * 64;
    int isbf = flag[0];

    __shared__ __attribute__((aligned(16))) u16 KV0[16384];   // 32 KB
    __shared__ __attribute__((aligned(16))) u16 KV1[16384];   // 32 KB
    __shared__ __attribute__((aligned(16))) u16 Ps[4096];     // P 64x64 bf16
    __shared__ float al_s[64];
    __shared__ float il_s[64];

    int tid = threadIdx.x;
    int w = tid >> 6, lane = tid & 63, quad = lane >> 4, l16 = lane & 15;
    int sw = l16 & 7;

    const u16* Qb = Q  + (size_t)b * 2048 * 512;
    const u16* Kb = K  + (size_t)b * 2048 * 512;
    const u16* Vb = Vt + (size_t)b * 512 * 2048;

    if (kt0 < kt1) LOADK(KV0, kt0 * 64, 0);    // prefetch first K half0

    // Q fragments in regs: rows w*16+l16, qf[g] = d-granule g (static idx only)
    short8 qf[16];
    {
        const u16* Qrow = &Qb[(size_t)(q0 + w * 16 + l16) * 512];
        #pragma unroll
        for (int g = 0; g < 16; g++)
            qf[g] = *(const short8*)&Qrow[g * 32 + quad * 8];
    }

    float4v accO0[4][4] = {};     // d = 0*256 + w*64 + dt*16 + l16
    float4v accO1[4][4] = {};     // d = 1*256 + w*64 + dt*16 + l16
    float4v accS[4] = {};         // keys nt*16+l16, rows w*16+quad*4+r
    short8 pf[4][2];
    float mrow[4] = {-1e30f, -1e30f, -1e30f, -1e30f};
    float lrow[4] = {0.f, 0.f, 0.f, 0.f};
    const float scale = 0.044194173824159216f;     // 1/sqrt(512)

    __syncthreads();

    for (int kt = kt0; kt < kt1; kt++) {
        int kB = kt * 64;

        // ---- ph0: prefetch K half1 -> KV1; S += Q0.K0 from KV0 ----
        LOADK(KV1, kB, 1);
        SSTEP(KV0, 0);
        __syncthreads();

        // ---- ph1: prefetch V half0 -> KV0; S += Q1.K1 from KV1; softmax ----
        LOADV(KV0, kB, 0);
        SSTEP(KV1, 1);
        {
            int diag = (kt == qt);
            float pv[4][4], alpha[4];
            #pragma unroll
            for (int r = 0; r < 4; r++) {
                float mx = -1e30f;
                #pragma unroll
                for (int nt = 0; nt < 4; nt++) {
                    float sv = accS[nt][r] * scale;
                    if (diag && (nt * 16 + l16 > w * 16 + quad * 4 + r)) sv = -1e30f;
                    pv[nt][r] = sv;
                    mx = fmaxf(mx, sv);
                }
                mx = fmaxf(mx, __shfl_xor(mx, 1));
                mx = fmaxf(mx, __shfl_xor(mx, 2));
                mx = fmaxf(mx, __shfl_xor(mx, 4));
                mx = fmaxf(mx, __shfl_xor(mx, 8));
                float mnew = fmaxf(mrow[r], mx);
                float a = __expf(mrow[r] - mnew);
                float sum = 0.f;
                #pragma unroll
                for (int nt = 0; nt < 4; nt++) {
                    pv[nt][r] = __expf(pv[nt][r] - mnew);
                    sum += pv[nt][r];
                }
                sum += __shfl_xor(sum, 1);
                sum += __shfl_xor(sum, 2);
                sum += __shfl_xor(sum, 4);
                sum += __shfl_xor(sum, 8);
                lrow[r] = lrow[r] * a + sum;
                mrow[r] = mnew;
                alpha[r] = a;
            }
            #pragma unroll
            for (int nt = 0; nt < 4; nt++)
                #pragma unroll
                for (int r = 0; r < 4; r++)
                    Ps[(w * 16 + quad * 4 + r) * 64 + nt * 16 + l16] = f2bf(pv[nt][r]);
            #pragma unroll
            for (int r = 0; r < 4; r++) al_s[w * 16 + quad * 4 + r] = alpha[r];
            #pragma unroll
            for (int nt = 0; nt < 4; nt++) accS[nt] = (float4v){0.f, 0.f, 0.f, 0.f};
        }
        __syncthreads();

        // ---- ph2: prefetch V half1 -> KV1; P-frags + rescale; O0 += P.V0 ----
        LOADV(KV1, kB, 1);
        {
            #pragma unroll
            for (int mt = 0; mt < 4; mt++)
                #pragma unroll
                for (int kk = 0; kk < 2; kk++)
                    pf[mt][kk] = *(const short8*)&Ps[(mt * 16 + l16) * 64 +
                                                     kk * 32 + quad * 8];
            float alf[4][4];
            #pragma unroll
            for (int mt = 0; mt < 4; mt++)
                #pragma unroll
                for (int r = 0; r < 4; r++)
                    alf[mt][r] = al_s[mt * 16 + quad * 4 + r];
            #pragma unroll
            for (int dt = 0; dt < 4; dt++)
                #pragma unroll
                for (int mt = 0; mt < 4; mt++)
                    #pragma unroll
                    for (int r = 0; r < 4; r++) {
                        accO0[dt][mt][r] *= alf[mt][r];
                        accO1[dt][mt][r] *= alf[mt][r];
                    }
        }
        PVSTEP(KV0, accO0);
        __syncthreads();

        // ---- ph3: prefetch next K half0 -> KV0; O1 += P.V1 from KV1 ----
        if (kt + 1 < kt1) LOADK(KV0, kB + 64, 0);
        PVSTEP(KV1, accO1);
        __syncthreads();
    }

    if (dosplit) {
        // ---- epilogue A: write unnormalized O (bf16) + per-row (m,l) ----
        if (l16 == 0) {
            #pragma unroll
            for (int r = 0; r < 4; r++) {
                int grow = b * 2048 + q0 + w * 16 + quad * 4 + r;
                ml[h * 16384 + grow] = make_float2(mrow[r], lrow[r]);
            }
        }
        #pragma unroll
        for (int dt = 0; dt < 4; dt++) {
            int dg = w * 64 + dt * 16 + l16;
            #pragma unroll
            for (int mt = 0; mt < 4; mt++)
                #pragma unroll
                for (int r = 0; r < 4; r++) {
                    int grow = b * 2048 + q0 + mt * 16 + quad * 4 + r;
                    size_t base = ((size_t)h * 16384 + grow) * 512;
                    Opart[base + dg]       = f2bf(accO0[dt][mt][r]);
                    Opart[base + dg + 256] = f2bf(accO1[dt][mt][r]);
                }
        }
    } else {
        // ---- epilogue B: share 1/l, normalize, write out[..., 512:1024] ----
        #pragma unroll
        for (int r = 0; r < 4; r++) il_s[w * 16 + quad * 4 + r] = 1.0f / lrow[r];
        __syncthreads();
        float invl[4][4];
        #pragma unroll
        for (int mt = 0; mt < 4; mt++)
            #pragma unroll
            for (int r = 0; r < 4; r++) invl[mt][r] = il_s[mt * 16 + quad * 4 + r];
        u16*   o16 = (u16*)out;
        float* o32 = (float*)out;
        #pragma unroll
        for (int dt = 0; dt < 4; dt++) {
            int dg0 = 512 + w * 64 + dt * 16 + l16;
            #pragma unroll
            for (int mt = 0; mt < 4; mt++)
                #pragma unroll
                for (int r = 0; r < 4; r++) {
                    int rowg = q0 + mt * 16 + quad * 4 + r;
                    size_t base = ((size_t)b * 2048 + rowg) * 1024;
                    float v0 = accO0[dt][mt][r] * invl[mt][r];
                    float v1 = accO1[dt][mt][r] * invl[mt][r];
                    if (isbf) {
                        o16[base + dg0]       = f2bf(v0);
                        o16[base + dg0 + 256] = f2bf(v1);
                    } else {
                        o32[base + dg0]       = v0;
                        o32[base + dg0 + 256] = v1;
                    }
                }
        }
    }
}

// ---------------- Kernel 6: split-K combine ---------------------------------
// out[grow, 512+d] = (a0*O0 + a1*O1) / (a0*l0 + a1*l1), a_h = exp(m_h - m).
__global__ __launch_bounds__(256) void combine_k(
        const u16* __restrict__ Opart, const float2* __restrict__ ml,
        const int* __restrict__ flag, void* __restrict__ out) {
    int tid = threadIdx.x;
    int grow = blockIdx.x * 4 + (tid >> 6);
    int d0 = (tid & 63) * 8;
    float2 ml0 = ml[grow], ml1 = ml[16384 + grow];
    float m = fmaxf(ml0.x, ml1.x);
    float a0 = __expf(ml0.x - m), a1 = __expf(ml1.x - m);
    float il = 1.0f / (ml0.y * a0 + ml1.y * a1);
    a0 *= il; a1 *= il;
    uint4 v0 = *(const uint4*)&Opart[(size_t)grow * 512 + d0];
    uint4 v1 = *(const uint4*)&Opart[(size_t)(16384 + grow) * 512 + d0];
    const u16* u0 = (const u16*)&v0;
    const u16* u1 = (const u16*)&v1;
    float res[8];
    #pragma unroll
    for (int i = 0; i < 8; i++)
        res[i] = bf2f(u0[i]) * a0 + bf2f(u1[i]) * a1;
    size_t base = (size_t)grow * 1024 + 512 + d0;
    if (flag[0]) {
        union { u16 us[8]; uint4 v; } pk;
        #pragma unroll
        for (int i = 0; i < 8; i++) pk.us[i] = f2bf(res[i]);
        *(uint4*)((u16*)out + base) = pk.v;
    } else {
        float* o = (float*)out + base;
        *(float4*)o = make_float4(res[0], res[1], res[2], res[3]);
        *(float4*)(o + 4) = make_float4(res[4], res[5], res[6], res[7]);
    }
}

// ---------------- launcher --------------------------------------------------
extern "C" void kernel_launch(void* const* d_in, const int* in_sizes, int n_in,
                              void* d_out, int out_size, void* d_ws, size_t ws_size,
                              hipStream_t stream) {
    const void* x  = d_in[0];
    const void* Wq = d_in[1];
    const void* bq = d_in[2];
    const void* Wk = d_in[3];
    const void* bk = d_in[4];
    const void* Wv = d_in[5];
    const void* bv = d_in[6];

    u16* base = (u16*)d_ws;
    int* flag = (int*)base;                         // 16 B
    u16* Wt   = base + 8;                           // 3*512*512
    u16* bb   = Wt + 786432;                        // 1536 (pad 1544)
    u16* xb   = bb + 1544;                          // 8,388,608
    u16* Qw   = xb + 8388608;
    u16* Kw   = Qw + 8388608;
    u16* Vtw  = Kw + 8388608;                       // Vt[b][d][t]
    u16* Opart = Vtw + 8388608;                     // 2*16384*512 u16 = 33.5 MB
    float2* mlb = (float2*)(Opart + 16777216);      // 2*16384 float2 = 256 KB

    // bytes needed for split-K partials
    size_t need = ((size_t)(Opart - base) + 16777216) * 2 + 262144;
    int dosplit = (ws_size >= need) ? 1 : 0;

    hipLaunchKernelGGL(detect_k, dim3(1), dim3(256), 0, stream, (const u32*)x, flag);
    hipLaunchKernelGGL(convx_k, dim3(4096), dim3(256), 0, stream, x, flag, xb, d_out);
    hipLaunchKernelGGL(convw_k, dim3(1024, 3), dim3(256), 0, stream, Wq, Wk, Wv, flag, Wt);
    hipLaunchKernelGGL(convb_k, dim3(6), dim3(256), 0, stream, bq, bk, bv, flag, bb);
    hipLaunchKernelGGL(proj_k, dim3(128, 4, 3), dim3(256), 0, stream, xb, Wt, bb, Qw, Kw, Vtw);
    if (dosplit) {
        hipLaunchKernelGGL(attn_k, dim3(512), dim3(256), 0, stream,
                           Qw, Kw, Vtw, flag, d_out, Opart, mlb, 1);
        hipLaunchKernelGGL(combine_k, dim3(4096), dim3(256), 0, stream,
                           Opart, mlb, flag, d_out);
    } else {
        hipLaunchKernelGGL(attn_k, dim3(256), dim3(256), 0, stream,
                           Qw, Kw, Vtw, flag, d_out, Opart, mlb, 0);
    }
}

// Round 8
// 290.820 us; speedup vs baseline: 1.4969x; 1.4969x over previous
//
#include <hip/hip_runtime.h>

// SelfAttentionBlock: x[8,2048,512]; Wq/Wk/Wv [512,512]; bq/bk/bv [512].
// out[8,2048,1024] = concat(x, causal_softmax(QK^T/sqrt(512)) @ V).
// v8: v5 attn interior (208 VGPR, no spill) + split-K (512 tasks, balanced
// pairing so 2 co-resident blocks/CU sum to ~16.5 tile-units) + combine.

#define DEV __device__ __forceinline__

typedef unsigned short u16;
typedef unsigned int u32;
typedef __attribute__((ext_vector_type(8))) short short8;   // 8 bf16 = 4 VGPRs
typedef __attribute__((ext_vector_type(4))) float float4v;  // MFMA C/D frag

DEV u16 f2bf(float f) {
    u32 u = __float_as_uint(f);
    return (u16)((u + 0x7FFFu + ((u >> 16) & 1u)) >> 16);
}
DEV float bf2f(u16 h) { return __uint_as_float(((u32)h) << 16); }

DEV float4v mfma16(short8 a, short8 b, float4v c) {
    return __builtin_amdgcn_mfma_f32_16x16x32_bf16(a, b, c, 0, 0, 0);
}

// async global->LDS, 16B per lane; LDS dest = wave-uniform base + lane*16
#define GLD16(gptr, lptr)                                                     \
    __builtin_amdgcn_global_load_lds(                                         \
        (const __attribute__((address_space(1))) void*)(gptr),                \
        (__attribute__((address_space(3))) void*)(lptr), 16, 0, 0)

// ---------------- Kernel 0: detect input dtype ------------------------------
__global__ void detect_k(const u32* __restrict__ xw, int* __restrict__ flag) {
    __shared__ int sh[256];
    int tid = threadIdx.x;
    u32 w = xw[tid * 64];
    int e = (w >> 7) & 0xFF;
    sh[tid] = (e >= 0x60 && e <= 0x90) ? 1 : 0;
    __syncthreads();
    for (int s = 128; s > 0; s >>= 1) {
        if (tid < s) sh[tid] += sh[tid + s];
        __syncthreads();
    }
    if (tid == 0) flag[0] = (sh[0] > 128) ? 1 : 0;   // 1 = bf16
}

// ---------------- Kernel 1: canonicalize x -> xb; also write out[...,0:512] -
__global__ void convx_k(const void* __restrict__ x, const int* __restrict__ flag,
                        u16* __restrict__ xb, void* __restrict__ out) {
    int i0 = (blockIdx.x * 256 + threadIdx.x) * 8;
    int row = i0 >> 9, col = i0 & 511;
    if (flag[0]) {
        uint4 v = *(const uint4*)((const u16*)x + i0);
        *(uint4*)&xb[i0] = v;
        *(uint4*)((u16*)out + (size_t)row * 1024 + col) = v;
    } else {
        const float* xf = (const float*)x;
        float4 f0 = *(const float4*)(xf + i0);
        float4 f1 = *(const float4*)(xf + i0 + 4);
        union { u16 us[8]; uint4 v; } pk;
        pk.us[0] = f2bf(f0.x); pk.us[1] = f2bf(f0.y);
        pk.us[2] = f2bf(f0.z); pk.us[3] = f2bf(f0.w);
        pk.us[4] = f2bf(f1.x); pk.us[5] = f2bf(f1.y);
        pk.us[6] = f2bf(f1.z); pk.us[7] = f2bf(f1.w);
        *(uint4*)&xb[i0] = pk.v;
        float* o = (float*)out + (size_t)row * 1024 + col;
        *(float4*)o = f0; *(float4*)(o + 4) = f1;
    }
}

// ---------------- Kernel 2: transpose+canonicalize weights, and biases ------
__global__ void convwb_k(const void* __restrict__ Wq, const void* __restrict__ Wk,
                         const void* __restrict__ Wv, const void* __restrict__ bq,
                         const void* __restrict__ bk, const void* __restrict__ bv,
                         const int* __restrict__ flag,
                         u16* __restrict__ Wt, u16* __restrict__ bbuf) {
    int z = blockIdx.y;
    if (blockIdx.x >= 1024) {                      // bias blocks (2 per z)
        int i = (blockIdx.x - 1024) * 256 + threadIdx.x;   // 0..511
        const void* s = (z == 0) ? bq : ((z == 1) ? bk : bv);
        bbuf[z * 512 + i] = flag[0] ? ((const u16*)s)[i]
                                    : f2bf(((const float*)s)[i]);
        return;
    }
    const void* W = (z == 0) ? Wq : ((z == 1) ? Wk : Wv);
    int flat = blockIdx.x * 256 + threadIdx.x;     // = n*512 + k
    int n = flat >> 9, k = flat & 511;
    u16 v = flag[0] ? ((const u16*)W)[k * 512 + n]
                    : f2bf(((const float*)W)[k * 512 + n]);
    Wt[z * 262144 + flat] = v;
}

// ---------------- Kernel 4: QKV projection GEMM -----------------------------
__global__ __launch_bounds__(256) void proj_k(
        const u16* __restrict__ x, const u16* __restrict__ Wt,
        const u16* __restrict__ bb,
        u16* __restrict__ Qo, u16* __restrict__ Ko, u16* __restrict__ Vt_out) {
    int z = blockIdx.z;
    const u16* Wz = Wt + z * 262144;                       // Wz[n][k]
    const u16* bias = bb + z * 512;
    int mBase = blockIdx.x * 128;
    int nBase = blockIdx.y * 128;

    __shared__ __attribute__((aligned(16))) u16 Xs[128 * 32];
    __shared__ __attribute__((aligned(16))) u16 Ws[128 * 32];

    int tid = threadIdx.x;
    int w = tid >> 6, lane = tid & 63, quad = lane >> 4, l16 = lane & 15;
    int wr = (w >> 1) * 64, wc = (w & 1) * 64;

    float4v acc[4][4] = {};

    for (int k0 = 0; k0 < 512; k0 += 32) {
        #pragma unroll
        for (int gg = 0; gg < 2; gg++) {                   // 1KB granules
            int g = w * 2 + gg;
            int row = g * 16 + (lane >> 2);
            int col8 = lane & 3;
            GLD16(&x [(size_t)(mBase + row) * 512 + k0 + col8 * 8], &Xs[g * 512]);
            GLD16(&Wz[(size_t)(nBase + row) * 512 + k0 + col8 * 8], &Ws[g * 512]);
        }
        __syncthreads();

        short8 a[4], b[4];
        #pragma unroll
        for (int mt = 0; mt < 4; mt++)
            a[mt] = *(const short8*)&Xs[(wr + mt * 16 + l16) * 32 + quad * 8];
        #pragma unroll
        for (int nt = 0; nt < 4; nt++)
            b[nt] = *(const short8*)&Ws[(wc + nt * 16 + l16) * 32 + quad * 8];
        #pragma unroll
        for (int mt = 0; mt < 4; mt++)
            #pragma unroll
            for (int nt = 0; nt < 4; nt++)
                acc[mt][nt] = mfma16(a[mt], b[nt], acc[mt][nt]);
        __syncthreads();
    }

    #pragma unroll
    for (int nt = 0; nt < 4; nt++) {
        int n = nBase + wc + nt * 16 + l16;
        float bval = bf2f(bias[n]);
        #pragma unroll
        for (int mt = 0; mt < 4; mt++) {
            int m0 = mBase + wr + mt * 16 + quad * 4;
            float4v v = acc[mt][nt];
            if (z == 2) {
                int bbi = m0 >> 11, tt = m0 & 2047;        // Vt[b][d=n][t]
                u16 t0 = f2bf(v[0] + bval), t1 = f2bf(v[1] + bval);
                u16 t2 = f2bf(v[2] + bval), t3 = f2bf(v[3] + bval);
                uint2 pk = make_uint2((u32)t0 | ((u32)t1 << 16), (u32)t2 | ((u32)t3 << 16));
                *(uint2*)&Vt_out[((size_t)bbi * 512 + n) * 2048 + tt] = pk;
            } else {
                u16* dst = (z == 0) ? Qo : Ko;
                #pragma unroll
                for (int r = 0; r < 4; r++)
                    dst[(size_t)(m0 + r) * 512 + n] = f2bf(v[r] + bval);
            }
        }
    }
}

// ---------------- Kernel 5: flash attention v8 ------------------------------
// v5 interior (no reg cap -> 208 VGPR, no spill). Split-K over 2 key-halves.
// Task order: blocks 0..255 -> qt 31..16 (heavy), 256..511 -> qt 0..15, so
// round-robin pairing (c, c+256) sums to ~16.5 tile-units per CU and keeps
// one batch per XCD.

#define LOADK(dst, kB, half)                                                  \
    { _Pragma("unroll")                                                       \
      for (int j = 0; j < 8; j++) {                                           \
        int row2 = 2 * (j * 4 + w);                                           \
        int row = row2 + (lane >> 5);                                         \
        int col8 = lane & 31;                                                 \
        GLD16(&Kb[(size_t)((kB) + row) * 512 + (half) * 256 +                 \
                  ((col8 ^ (row & 7)) << 3)], &dst[row2 * 256]);              \
      } }

#define LOADV(dst, kB, half)                                                  \
    { _Pragma("unroll")                                                       \
      for (int j = 0; j < 8; j++) {                                           \
        int blk8 = 8 * (j * 4 + w);                                           \
        int dl = blk8 + (lane >> 3);                                          \
        int col8 = lane & 7;                                                  \
        GLD16(&Vb[(size_t)((half) * 256 + dl) * 2048 + (kB) +                 \
                  ((col8 ^ (dl & 7)) << 3)], &dst[blk8 * 64]);                \
      } }

#define SSTEP(buf, h)                                                         \
    { _Pragma("unroll")                                                       \
      for (int kk = 0; kk < 8; kk++) {                                        \
        _Pragma("unroll")                                                     \
        for (int nt = 0; nt < 4; nt++) {                                      \
          short8 bf = *(const short8*)&buf[(nt * 16 + l16) * 256 +            \
                                           (((kk * 4 + quad) ^ sw) << 3)];    \
          accS[nt] = mfma16(qf[(h) * 8 + kk], bf, accS[nt]);                  \
        } } }

#define PVSTEP(buf, accO)                                                     \
    { _Pragma("unroll")                                                       \
      for (int kk = 0; kk < 2; kk++) {                                        \
        _Pragma("unroll")                                                     \
        for (int dt = 0; dt < 4; dt++) {                                      \
          int rowv = w * 64 + dt * 16 + l16;                                  \
          short8 bf = *(const short8*)&buf[rowv * 64 +                        \
                                           (((kk * 4 + quad) ^ sw) << 3)];    \
          _Pragma("unroll")                                                   \
          for (int mt = 0; mt < 4; mt++)                                      \
            accO[dt][mt] = mfma16(pf[mt][kk], bf, accO[dt][mt]);              \
        } } }

__global__ __launch_bounds__(256, 1) void attn_k(
        const u16* __restrict__ Q, const u16* __restrict__ K,
        const u16* __restrict__ Vt, const int* __restrict__ flag,
        void* __restrict__ out, u16* __restrict__ Opart,
        float2* __restrict__ ml, int dosplit) {
    int blk = blockIdx.x;
    int b, qt, h, kt0, kt1;
    if (dosplit) {
        qt = (blk < 256) ? (31 - (blk >> 4)) : ((blk - 256) >> 4);
        h  = (blk >> 3) & 1;
        b  = blk & 7;
        int n = qt + 1, mid = n >> 1;
        kt0 = h ? mid : 0;
        kt1 = h ? n : mid;
    } else {
        qt = 31 - (blk >> 3);
        h  = 0;
        b  = blk & 7;
        kt0 = 0; kt1 = qt + 1;
    }
    int q0 = qt * 64;
    int isbf = flag[0];

    __shared__ __attribute__((aligned(16))) u16 KV0[16384];   // 32 KB
    __shared__ __attribute__((aligned(16))) u16 KV1[16384];   // 32 KB
    __shared__ __attribute__((aligned(16))) u16 Ps[4096];     // P 64x64 bf16
    __shared__ float al_s[64];
    __shared__ float il_s[64];

    int tid = threadIdx.x;
    int w = tid >> 6, lane = tid & 63, quad = lane >> 4, l16 = lane & 15;
    int sw = l16 & 7;

    const u16* Qb = Q  + (size_t)b * 2048 * 512;
    const u16* Kb = K  + (size_t)b * 2048 * 512;
    const u16* Vb = Vt + (size_t)b * 512 * 2048;

    if (kt0 < kt1) LOADK(KV0, kt0 * 64, 0);    // prefetch first K half0

    // Q fragments in regs: rows w*16+l16, qf[g] = d-granule g (static idx only)
    short8 qf[16];
    {
        const u16* Qrow = &Qb[(size_t)(q0 + w * 16 + l16) * 512];
        #pragma unroll
        for (int g = 0; g < 16; g++)
            qf[g] = *(const short8*)&Qrow[g * 32 + quad * 8];
    }

    float4v accO0[4][4] = {};     // d = 0*256 + w*64 + dt*16 + l16
    float4v accO1[4][4] = {};     // d = 1*256 + w*64 + dt*16 + l16
    float4v accS[4] = {};         // keys nt*16+l16, rows w*16+quad*4+r
    short8 pf[4][2];
    float mrow[4] = {-1e30f, -1e30f, -1e30f, -1e30f};
    float lrow[4] = {0.f, 0.f, 0.f, 0.f};
    const float scale = 0.044194173824159216f;     // 1/sqrt(512)

    __syncthreads();

    for (int kt = kt0; kt < kt1; kt++) {
        int kB = kt * 64;

        // ---- ph0: prefetch K half1 -> KV1; S += Q0.K0 from KV0 ----
        LOADK(KV1, kB, 1);
        SSTEP(KV0, 0);
        __syncthreads();

        // ---- ph1: prefetch V half0 -> KV0; S += Q1.K1 from KV1; softmax ----
        LOADV(KV0, kB, 0);
        SSTEP(KV1, 1);
        {
            int diag = (kt == qt);
            float pv[4][4], alpha[4];
            #pragma unroll
            for (int r = 0; r < 4; r++) {
                float mx = -1e30f;
                #pragma unroll
                for (int nt = 0; nt < 4; nt++) {
                    float sv = accS[nt][r] * scale;
                    if (diag && (nt * 16 + l16 > w * 16 + quad * 4 + r)) sv = -1e30f;
                    pv[nt][r] = sv;
                    mx = fmaxf(mx, sv);
                }
                mx = fmaxf(mx, __shfl_xor(mx, 1));
                mx = fmaxf(mx, __shfl_xor(mx, 2));
                mx = fmaxf(mx, __shfl_xor(mx, 4));
                mx = fmaxf(mx, __shfl_xor(mx, 8));
                float mnew = fmaxf(mrow[r], mx);
                float a = __expf(mrow[r] - mnew);
                float sum = 0.f;
                #pragma unroll
                for (int nt = 0; nt < 4; nt++) {
                    pv[nt][r] = __expf(pv[nt][r] - mnew);
                    sum += pv[nt][r];
                }
                sum += __shfl_xor(sum, 1);
                sum += __shfl_xor(sum, 2);
                sum += __shfl_xor(sum, 4);
                sum += __shfl_xor(sum, 8);
                lrow[r] = lrow[r] * a + sum;
                mrow[r] = mnew;
                alpha[r] = a;
            }
            #pragma unroll
            for (int nt = 0; nt < 4; nt++)
                #pragma unroll
                for (int r = 0; r < 4; r++)
                    Ps[(w * 16 + quad * 4 + r) * 64 + nt * 16 + l16] = f2bf(pv[nt][r]);
            #pragma unroll
            for (int r = 0; r < 4; r++) al_s[w * 16 + quad * 4 + r] = alpha[r];
            #pragma unroll
            for (int nt = 0; nt < 4; nt++) accS[nt] = (float4v){0.f, 0.f, 0.f, 0.f};
        }
        __syncthreads();

        // ---- ph2: prefetch V half1 -> KV1; P-frags + rescale; O0 += P.V0 ----
        LOADV(KV1, kB, 1);
        {
            #pragma unroll
            for (int mt = 0; mt < 4; mt++)
                #pragma unroll
                for (int kk = 0; kk < 2; kk++)
                    pf[mt][kk] = *(const short8*)&Ps[(mt * 16 + l16) * 64 +
                                                     kk * 32 + quad * 8];
            float alf[4][4];
            #pragma unroll
            for (int mt = 0; mt < 4; mt++)
                #pragma unroll
                for (int r = 0; r < 4; r++)
                    alf[mt][r] = al_s[mt * 16 + quad * 4 + r];
            #pragma unroll
            for (int dt = 0; dt < 4; dt++)
                #pragma unroll
                for (int mt = 0; mt < 4; mt++)
                    #pragma unroll
                    for (int r = 0; r < 4; r++) {
                        accO0[dt][mt][r] *= alf[mt][r];
                        accO1[dt][mt][r] *= alf[mt][r];
                    }
        }
        PVSTEP(KV0, accO0);
        __syncthreads();

        // ---- ph3: prefetch next K half0 -> KV0; O1 += P.V1 from KV1 ----
        if (kt + 1 < kt1) LOADK(KV0, kB + 64, 0);
        PVSTEP(KV1, accO1);
        __syncthreads();
    }

    if (dosplit) {
        // ---- epilogue A: write unnormalized O (bf16) + per-row (m,l) ----
        if (l16 == 0) {
            #pragma unroll
            for (int r = 0; r < 4; r++) {
                int grow = b * 2048 + q0 + w * 16 + quad * 4 + r;
                ml[h * 16384 + grow] = make_float2(mrow[r], lrow[r]);
            }
        }
        #pragma unroll
        for (int dt = 0; dt < 4; dt++) {
            int dg = w * 64 + dt * 16 + l16;
            #pragma unroll
            for (int mt = 0; mt < 4; mt++)
                #pragma unroll
                for (int r = 0; r < 4; r++) {
                    int grow = b * 2048 + q0 + mt * 16 + quad * 4 + r;
                    size_t base = ((size_t)h * 16384 + grow) * 512;
                    Opart[base + dg]       = f2bf(accO0[dt][mt][r]);
                    Opart[base + dg + 256] = f2bf(accO1[dt][mt][r]);
                }
        }
    } else {
        // ---- epilogue B: share 1/l, normalize, write out[..., 512:1024] ----
        #pragma unroll
        for (int r = 0; r < 4; r++) il_s[w * 16 + quad * 4 + r] = 1.0f / lrow[r];
        __syncthreads();
        float invl[4][4];
        #pragma unroll
        for (int mt = 0; mt < 4; mt++)
            #pragma unroll
            for (int r = 0; r < 4; r++) invl[mt][r] = il_s[mt * 16 + quad * 4 + r];
        u16*   o16 = (u16*)out;
        float* o32 = (float*)out;
        #pragma unroll
        for (int dt = 0; dt < 4; dt++) {
            int dg0 = 512 + w * 64 + dt * 16 + l16;
            #pragma unroll
            for (int mt = 0; mt < 4; mt++)
                #pragma unroll
                for (int r = 0; r < 4; r++) {
                    int rowg = q0 + mt * 16 + quad * 4 + r;
                    size_t base = ((size_t)b * 2048 + rowg) * 1024;
                    float v0 = accO0[dt][mt][r] * invl[mt][r];
                    float v1 = accO1[dt][mt][r] * invl[mt][r];
                    if (isbf) {
                        o16[base + dg0]       = f2bf(v0);
                        o16[base + dg0 + 256] = f2bf(v1);
                    } else {
                        o32[base + dg0]       = v0;
                        o32[base + dg0 + 256] = v1;
                    }
                }
        }
    }
}

// ---------------- Kernel 6: split-K combine ---------------------------------
__global__ __launch_bounds__(256) void combine_k(
        const u16* __restrict__ Opart, const float2* __restrict__ ml,
        const int* __restrict__ flag, void* __restrict__ out) {
    int tid = threadIdx.x;
    int grow = blockIdx.x * 4 + (tid >> 6);
    int d0 = (tid & 63) * 8;
    float2 ml0 = ml[grow], ml1 = ml[16384 + grow];
    float m = fmaxf(ml0.x, ml1.x);
    float a0 = __expf(ml0.x - m), a1 = __expf(ml1.x - m);
    float il = 1.0f / (ml0.y * a0 + ml1.y * a1);
    a0 *= il; a1 *= il;
    uint4 v0 = *(const uint4*)&Opart[(size_t)grow * 512 + d0];
    uint4 v1 = *(const uint4*)&Opart[(size_t)(16384 + grow) * 512 + d0];
    const u16* u0 = (const u16*)&v0;
    const u16* u1 = (const u16*)&v1;
    float res[8];
    #pragma unroll
    for (int i = 0; i < 8; i++)
        res[i] = bf2f(u0[i]) * a0 + bf2f(u1[i]) * a1;
    size_t base = (size_t)grow * 1024 + 512 + d0;
    if (flag[0]) {
        union { u16 us[8]; uint4 v; } pk;
        #pragma unroll
        for (int i = 0; i < 8; i++) pk.us[i] = f2bf(res[i]);
        *(uint4*)((u16*)out + base) = pk.v;
    } else {
        float* o = (float*)out + base;
        *(float4*)o = make_float4(res[0], res[1], res[2], res[3]);
        *(float4*)(o + 4) = make_float4(res[4], res[5], res[6], res[7]);
    }
}

// ---------------- launcher --------------------------------------------------
extern "C" void kernel_launch(void* const* d_in, const int* in_sizes, int n_in,
                              void* d_out, int out_size, void* d_ws, size_t ws_size,
                              hipStream_t stream) {
    const void* x  = d_in[0];
    const void* Wq = d_in[1];
    const void* bq = d_in[2];
    const void* Wk = d_in[3];
    const void* bk = d_in[4];
    const void* Wv = d_in[5];
    const void* bv = d_in[6];

    u16* base = (u16*)d_ws;
    int* flag = (int*)base;                         // 16 B
    u16* Wt   = base + 8;                           // 3*512*512
    u16* bb   = Wt + 786432;                        // 1536 (pad 1544)
    u16* xb   = bb + 1544;                          // 8,388,608
    u16* Qw   = xb + 8388608;
    u16* Kw   = Qw + 8388608;
    u16* Vtw  = Kw + 8388608;                       // Vt[b][d][t]
    u16* Opart = Vtw + 8388608;                     // 2*16384*512 u16 = 33.5 MB
    float2* mlb = (float2*)(Opart + 16777216);      // 2*16384 float2 = 256 KB

    size_t need = ((size_t)(Opart - base) + 16777216) * 2 + 262144;
    int dosplit = (ws_size >= need) ? 1 : 0;

    hipLaunchKernelGGL(detect_k, dim3(1), dim3(256), 0, stream, (const u32*)x, flag);
    hipLaunchKernelGGL(convx_k, dim3(4096), dim3(256), 0, stream, x, flag, xb, d_out);
    hipLaunchKernelGGL(convwb_k, dim3(1026, 3), dim3(256), 0, stream,
                       Wq, Wk, Wv, bq, bk, bv, flag, Wt, bb);
    hipLaunchKernelGGL(proj_k, dim3(128, 4, 3), dim3(256), 0, stream, xb, Wt, bb, Qw, Kw, Vtw);
    if (dosplit) {
        hipLaunchKernelGGL(attn_k, dim3(512), dim3(256), 0, stream,
                           Qw, Kw, Vtw, flag, d_out, Opart, mlb, 1);
        hipLaunchKernelGGL(combine_k, dim3(4096), dim3(256), 0, stream,
                           Opart, mlb, flag, d_out);
    } else {
        hipLaunchKernelGGL(attn_k, dim3(256), dim3(256), 0, stream,
                           Qw, Kw, Vtw, flag, d_out, Opart, mlb, 0);
    }
}